// Round 5
// baseline (386.306 us; speedup 1.0000x reference)
//
#include <hip/hip_runtime.h>
#include <math.h>
#include <float.h>

#define D 256
#define K 1024
#define NROWS 32768
#define MARGIN 1.0f     // z-margin for np-replica near-tie refinement (fp16 fast-z)
#define MAXCAND 12

#define LOSS_OFF 8388608
#define IDX_OFF  8388609

typedef _Float16 h8 __attribute__((ext_vector_type(8)));
typedef _Float16 h4 __attribute__((ext_vector_type(4)));
typedef float    v4f __attribute__((ext_vector_type(4)));

// ---- numpy pairwise sum replica for sum(a*a) over 128 contiguous floats ----
__device__ __forceinline__ float np_sq_block128(const float* a) {
    float r0 = __fmul_rn(a[0], a[0]);
    float r1 = __fmul_rn(a[1], a[1]);
    float r2 = __fmul_rn(a[2], a[2]);
    float r3 = __fmul_rn(a[3], a[3]);
    float r4 = __fmul_rn(a[4], a[4]);
    float r5 = __fmul_rn(a[5], a[5]);
    float r6 = __fmul_rn(a[6], a[6]);
    float r7 = __fmul_rn(a[7], a[7]);
    for (int i = 8; i < 128; i += 8) {
        r0 = __fadd_rn(r0, __fmul_rn(a[i + 0], a[i + 0]));
        r1 = __fadd_rn(r1, __fmul_rn(a[i + 1], a[i + 1]));
        r2 = __fadd_rn(r2, __fmul_rn(a[i + 2], a[i + 2]));
        r3 = __fadd_rn(r3, __fmul_rn(a[i + 3], a[i + 3]));
        r4 = __fadd_rn(r4, __fmul_rn(a[i + 4], a[i + 4]));
        r5 = __fadd_rn(r5, __fmul_rn(a[i + 5], a[i + 5]));
        r6 = __fadd_rn(r6, __fmul_rn(a[i + 6], a[i + 6]));
        r7 = __fadd_rn(r7, __fmul_rn(a[i + 7], a[i + 7]));
    }
    float tA = __fadd_rn(__fadd_rn(r0, r1), __fadd_rn(r2, r3));
    float tB = __fadd_rn(__fadd_rn(r4, r5), __fadd_rn(r6, r7));
    return __fadd_rn(tA, tB);
}

// ---- fused: codebook norms (numpy-exact) + fp32->fp16 convert --------------
__global__ void vq_prep(const float* __restrict__ cb, float* __restrict__ b2,
                        _Float16* __restrict__ c16) {
    int k = blockIdx.x * 256 + threadIdx.x;
    if (k >= K) return;
    const float* c = cb + (size_t)k * D;
    b2[k] = __fadd_rn(np_sq_block128(c), np_sq_block128(c + 128));
    const float4* c4 = (const float4*)c;
    h4* o4 = (h4*)(c16 + (size_t)k * D);
    #pragma unroll 8
    for (int i = 0; i < 64; ++i) {
        float4 v = c4[i];
        h4 o = { (_Float16)v.x, (_Float16)v.y, (_Float16)v.z, (_Float16)v.w };
        o4[i] = o;
    }
}

// ---- fused MFMA distance GEMM + argmin + softmax stats + outputs -----------
// Block: 256 thr = 4 waves = 4 code-quarters; each wave: 32 rows x 256 codes.
// B staged per 32-dim K-step into 64KB LDS in exact fragment-lane order.
__global__ __launch_bounds__(256, 2)
void vq_mfma(const float* __restrict__ x, const float* __restrict__ cb,
             const _Float16* __restrict__ c16, const float* __restrict__ b2,
             float* __restrict__ avg_acc, float* __restrict__ scal,
             float* __restrict__ out)
{
    __shared__ __align__(16) float4 bbuf[4096];   // 64 KB B-stage
    __shared__ float mred[4][32];
    __shared__ int   kred[4][32];
    __shared__ float sred[4][32];
    __shared__ float tred[4][32];
    __shared__ int   bkl[32];
    __shared__ int   candn[32];
    __shared__ int   candk[32][MAXCAND];
    __shared__ __align__(16) float xbuf[256];

    const int t   = threadIdx.x;
    const int w   = t >> 6;        // wave = code-quarter q (0..3)
    const int q   = w;
    const int l64 = t & 63;
    const int qd  = l64 >> 4;      // k-chunk (A/B) / row-subgroup (C)
    const int ln  = l64 & 15;      // m (A) / n (B) / col (C)
    const int r0  = blockIdx.x * 32;

    if (t < 32) candn[t] = 0;

    v4f acc[2][16];                // [row-tile][code-tile]
    #pragma unroll
    for (int rt = 0; rt < 2; ++rt)
        #pragma unroll
        for (int tt = 0; tt < 16; ++tt) acc[rt][tt] = (v4f)0.f;

    const float4* cg4   = (const float4*)c16;      // code row = 32 float4s
    const float*  ab[2] = { x + (size_t)(r0 + ln) * D,
                            x + (size_t)(r0 + 16 + ln) * D };

    // ---- prefetch step 0: B-stage slots + A fragments ----
    float4 pb[16], pa[4];
    #pragma unroll
    for (int kk = 0; kk < 16; ++kk) {
        int id   = t + 256 * kk;                    // LDS slot = global frag slot
        int code = ((id >> 6) << 4) | (id & 15);    // tile*16 + ln
        int qq   = (id >> 4) & 3;
        pb[kk] = cg4[code * 32 + qq];               // s=0
    }
    #pragma unroll
    for (int rt = 0; rt < 2; ++rt) {
        pa[2 * rt]     = *(const float4*)(ab[rt] + qd * 8);
        pa[2 * rt + 1] = *(const float4*)(ab[rt] + qd * 8 + 4);
    }

    for (int s = 0; s < 8; ++s) {
        __syncthreads();                            // prev-step readers done
        #pragma unroll
        for (int kk = 0; kk < 16; ++kk)
            bbuf[t + 256 * kk] = pb[kk];
        __syncthreads();                            // stage visible

        h8 af[2];
        #pragma unroll
        for (int rt = 0; rt < 2; ++rt) {
            float4 a0 = pa[2 * rt], a1 = pa[2 * rt + 1];
            af[rt][0] = (_Float16)a0.x; af[rt][1] = (_Float16)a0.y;
            af[rt][2] = (_Float16)a0.z; af[rt][3] = (_Float16)a0.w;
            af[rt][4] = (_Float16)a1.x; af[rt][5] = (_Float16)a1.y;
            af[rt][6] = (_Float16)a1.z; af[rt][7] = (_Float16)a1.w;
        }
        if (s < 7) {                                // prefetch s+1 during compute
            #pragma unroll
            for (int kk = 0; kk < 16; ++kk) {
                int id   = t + 256 * kk;
                int code = ((id >> 6) << 4) | (id & 15);
                int qq   = (id >> 4) & 3;
                pb[kk] = cg4[code * 32 + (s + 1) * 4 + qq];
            }
            #pragma unroll
            for (int rt = 0; rt < 2; ++rt) {
                pa[2 * rt]     = *(const float4*)(ab[rt] + (s + 1) * 32 + qd * 8);
                pa[2 * rt + 1] = *(const float4*)(ab[rt] + (s + 1) * 32 + qd * 8 + 4);
            }
        }
        #pragma unroll
        for (int tt = 0; tt < 16; ++tt) {
            h8 bf = *(const h8*)&bbuf[(16 * q + tt) * 64 + l64];
            acc[0][tt] = __builtin_amdgcn_mfma_f32_16x16x32_f16(af[0], bf, acc[0][tt], 0, 0, 0);
            acc[1][tt] = __builtin_amdgcn_mfma_f32_16x16x32_f16(af[1], bf, acc[1][tt], 0, 0, 0);
        }
    }

    // ---- z = 200*dot - 100*||c||^2 ----
    float b2c[16];
    #pragma unroll
    for (int tt = 0; tt < 16; ++tt) b2c[tt] = b2[256 * q + 16 * tt + ln];
    #pragma unroll
    for (int rt = 0; rt < 2; ++rt)
        #pragma unroll
        for (int tt = 0; tt < 16; ++tt)
            #pragma unroll
            for (int r = 0; r < 4; ++r)
                acc[rt][tt][r] = 200.f * acc[rt][tt][r] - 100.f * b2c[tt];

    // ---- per-row local max over this wave's 16 cols ----
    float m[2][4]; int bk[2][4];
    #pragma unroll
    for (int rt = 0; rt < 2; ++rt)
        #pragma unroll
        for (int r = 0; r < 4; ++r) { m[rt][r] = -INFINITY; bk[rt][r] = K; }
    #pragma unroll
    for (int tt = 0; tt < 16; ++tt)
        #pragma unroll
        for (int rt = 0; rt < 2; ++rt)
            #pragma unroll
            for (int r = 0; r < 4; ++r) {
                float z = acc[rt][tt][r];
                int code = 256 * q + 16 * tt + ln;
                if (z > m[rt][r]) { m[rt][r] = z; bk[rt][r] = code; }
            }
    #pragma unroll
    for (int off = 1; off < 16; off <<= 1)
        #pragma unroll
        for (int rt = 0; rt < 2; ++rt)
            #pragma unroll
            for (int r = 0; r < 4; ++r) {
                float om = __shfl_xor(m[rt][r], off);
                int   ok = __shfl_xor(bk[rt][r], off);
                if (om > m[rt][r] || (om == m[rt][r] && ok < bk[rt][r])) {
                    m[rt][r] = om; bk[rt][r] = ok;
                }
            }
    if (ln == 0)
        #pragma unroll
        for (int rt = 0; rt < 2; ++rt)
            #pragma unroll
            for (int r = 0; r < 4; ++r) {
                int rl = 16 * rt + 4 * qd + r;
                mred[q][rl] = m[rt][r]; kred[q][rl] = bk[rt][r];
            }
    __syncthreads();

    // ---- combine quarters (codes ascend with quarter -> '>' keeps low idx) --
    float mf[2][4]; int kf[2][4];
    #pragma unroll
    for (int rt = 0; rt < 2; ++rt)
        #pragma unroll
        for (int r = 0; r < 4; ++r) {
            int rl = 16 * rt + 4 * qd + r;
            mf[rt][r] = mred[0][rl]; kf[rt][r] = kred[0][rl];
            #pragma unroll
            for (int qq = 1; qq < 4; ++qq) {
                float mm = mred[qq][rl];
                if (mm > mf[rt][r]) { mf[rt][r] = mm; kf[rt][r] = kred[qq][rl]; }
            }
        }

    // ---- S,T with global max; candidate append; stash e-values ----
    float S[2][4] = {{0,0,0,0},{0,0,0,0}}, T[2][4] = {{0,0,0,0},{0,0,0,0}};
    #pragma unroll
    for (int tt = 0; tt < 16; ++tt)
        #pragma unroll
        for (int rt = 0; rt < 2; ++rt)
            #pragma unroll
            for (int r = 0; r < 4; ++r) {
                float z  = acc[rt][tt][r];
                float zz = z - mf[rt][r];
                float e  = __expf(zz);
                if (z > mf[rt][r] - MARGIN) {
                    int rl = 16 * rt + 4 * qd + r;
                    int slot = atomicAdd(&candn[rl], 1);
                    if (slot < MAXCAND) candk[rl][slot] = 256 * q + 16 * tt + ln;
                }
                S[rt][r] += e; T[rt][r] += zz * e;
                acc[rt][tt][r] = e;
            }
    #pragma unroll
    for (int off = 1; off < 16; off <<= 1)
        #pragma unroll
        for (int rt = 0; rt < 2; ++rt)
            #pragma unroll
            for (int r = 0; r < 4; ++r) {
                S[rt][r] += __shfl_xor(S[rt][r], off);
                T[rt][r] += __shfl_xor(T[rt][r], off);
            }
    if (ln == 0)
        #pragma unroll
        for (int rt = 0; rt < 2; ++rt)
            #pragma unroll
            for (int r = 0; r < 4; ++r) {
                int rl = 16 * rt + 4 * qd + r;
                sred[q][rl] = S[rt][r]; tred[q][rl] = T[rt][r];
            }
    __syncthreads();

    float iS[2][4];
    float hsum = 0.f;
    #pragma unroll
    for (int rt = 0; rt < 2; ++rt)
        #pragma unroll
        for (int r = 0; r < 4; ++r) {
            int rl = 16 * rt + 4 * qd + r;
            float Sf = sred[0][rl] + sred[1][rl] + sred[2][rl] + sred[3][rl];
            float Tf = tred[0][rl] + tred[1][rl] + tred[2][rl] + tred[3][rl];
            iS[rt][r] = 1.f / Sf;
            if (q == 0 && ln == 0) {
                bkl[rl] = kf[rt][r];
                hsum += Tf * iS[rt][r] - __logf(Sf);
            }
        }
    if (q == 0 && ln == 0) atomicAdd(&scal[1], hsum);

    // ---- sparse avg_probs emission ----
    #pragma unroll
    for (int tt = 0; tt < 16; ++tt)
        #pragma unroll
        for (int rt = 0; rt < 2; ++rt)
            #pragma unroll
            for (int r = 0; r < 4; ++r) {
                float p = acc[rt][tt][r] * iS[rt][r];
                if (p > 1e-12f)
                    atomicAdd(&avg_acc[256 * q + 16 * tt + ln], p);
            }
    __syncthreads();

    // ---- near-tie slow path (wave 0): numpy fp32-pipeline replica ----
    if (w == 0) {
        for (int row = 0; row < 32; ++row) {
            int tc = candn[row];
            if (tc < 2) continue;
            if (tc > MAXCAND) tc = MAXCAND;
            const float* xr = x + (size_t)(r0 + row) * D;
            *(float4*)&xbuf[l64 * 4] = *(const float4*)(xr + l64 * 4);
            float a2f = __fadd_rn(np_sq_block128(xbuf), np_sq_block128(xbuf + 128));
            float bestd = FLT_MAX; int bestk = K;
            for (int c = 0; c < tc; ++c) {
                int k = candk[row][c];
                double sdot = 0.0;
                #pragma unroll
                for (int dd = 0; dd < 4; ++dd)
                    sdot += (double)cb[(size_t)k * D + l64 * 4 + dd] *
                            (double)xbuf[l64 * 4 + dd];
                #pragma unroll
                for (int off = 32; off > 0; off >>= 1)
                    sdot += __shfl_xor(sdot, off);
                float abf = (float)sdot;
                float dnp = __fsub_rn(__fadd_rn(a2f, b2[k]), __fmul_rn(2.0f, abf));
                if (dnp < bestd || (dnp == bestd && k < bestk)) {
                    bestd = dnp; bestk = k;
                }
            }
            if (l64 == 0) bkl[row] = bestk;
        }
    }
    __syncthreads();

    // ---- outputs: wave w -> rows 8w..8w+7 ----
    float wmse = 0.f;
    #pragma unroll
    for (int rr = 0; rr < 8; ++rr) {
        int rl  = 8 * w + rr;
        int row = r0 + rl;
        int bk2 = bkl[rl];
        float4 xv = *(const float4*)(x  + (size_t)row * D + l64 * 4);
        float4 qv = *(const float4*)(cb + (size_t)bk2 * D + l64 * 4);
        float dx = qv.x - xv.x, dy = qv.y - xv.y, dz = qv.z - xv.z, dw = qv.w - xv.w;
        float4 st;
        st.x = xv.x + dx; st.y = xv.y + dy; st.z = xv.z + dz; st.w = xv.w + dw;
        *(float4*)(out + (size_t)row * D + l64 * 4) = st;
        if (l64 == 0) out[IDX_OFF + row] = (float)bk2;
        wmse += dx * dx + dy * dy + dz * dz + dw * dw;
    }
    #pragma unroll
    for (int off = 32; off > 0; off >>= 1)
        wmse += __shfl_xor(wmse, off);
    if (l64 == 0) atomicAdd(&scal[0], wmse);
}

// ---- finalize loss ----------------------------------------------------------
__global__ __launch_bounds__(1024)
void vq_fin(const float* __restrict__ avg_acc, const float* __restrict__ scal,
            float* __restrict__ out)
{
    __shared__ float sred[16];
    int t = threadIdx.x;
    float ap = avg_acc[t] * (1.f / 32768.f);
    float v = ap * logf(ap + 1e-5f);
    #pragma unroll
    for (int off = 32; off > 0; off >>= 1) v += __shfl_xor(v, off);
    if ((t & 63) == 0) sred[t >> 6] = v;
    __syncthreads();
    if (t == 0) {
        float s = 0.f;
        for (int w = 0; w < 16; ++w) s += sred[w];
        float avg_entropy = -s;
        float sampleH = -scal[1] * (1.f / 32768.f);
        float mse = scal[0] * (1.f / 8388608.f);
        float loss = 1.25f * mse + 0.1f * (sampleH - avg_entropy);
        out[LOSS_OFF] = loss;
    }
}

extern "C" void kernel_launch(void* const* d_in, const int* in_sizes, int n_in,
                              void* d_out, int out_size, void* d_ws, size_t ws_size,
                              hipStream_t stream)
{
    const float* x  = (const float*)d_in[0];
    const float* cb = (const float*)d_in[1];
    float* out = (float*)d_out;
    float* ws  = (float*)d_ws;
    float*     b2      = ws;                                   // [1024]
    float*     avg_acc = ws + K;                               // [1024]
    float*     scal    = ws + 2 * K;                           // [2]
    _Float16*  c16     = (_Float16*)((char*)d_ws + 16384);     // [1024*256]

    hipMemsetAsync(d_ws, 0, (2 * K + 2) * sizeof(float), stream);
    vq_prep<<<K / 256, 256, 0, stream>>>(cb, b2, c16);
    vq_mfma<<<NROWS / 32, 256, 0, stream>>>(x, cb, c16, b2, avg_acc, scal, out);
    vq_fin<<<1, 1024, 0, stream>>>(avg_acc, scal, out);
}

// Round 6
// 232.554 us; speedup vs baseline: 1.6611x; 1.6611x over previous
//
#include <hip/hip_runtime.h>
#include <math.h>
#include <float.h>

#define D 256
#define K 1024
#define NROWS 32768
#define MARGIN 1.0f     // z-margin for np-replica near-tie refinement (fp16 fast-z)
#define MAXCAND 12

#define LOSS_OFF 8388608
#define IDX_OFF  8388609

typedef _Float16 h8 __attribute__((ext_vector_type(8)));
typedef float    v4f __attribute__((ext_vector_type(4)));
typedef const __attribute__((address_space(1))) unsigned int* gas_u32p;
typedef __attribute__((address_space(3))) unsigned int* las_u32p;

// ---- numpy pairwise sum replica for sum(a*a) over 128 contiguous floats ----
__device__ __forceinline__ float np_sq_block128(const float* a) {
    float r0 = __fmul_rn(a[0], a[0]);
    float r1 = __fmul_rn(a[1], a[1]);
    float r2 = __fmul_rn(a[2], a[2]);
    float r3 = __fmul_rn(a[3], a[3]);
    float r4 = __fmul_rn(a[4], a[4]);
    float r5 = __fmul_rn(a[5], a[5]);
    float r6 = __fmul_rn(a[6], a[6]);
    float r7 = __fmul_rn(a[7], a[7]);
    for (int i = 8; i < 128; i += 8) {
        r0 = __fadd_rn(r0, __fmul_rn(a[i + 0], a[i + 0]));
        r1 = __fadd_rn(r1, __fmul_rn(a[i + 1], a[i + 1]));
        r2 = __fadd_rn(r2, __fmul_rn(a[i + 2], a[i + 2]));
        r3 = __fadd_rn(r3, __fmul_rn(a[i + 3], a[i + 3]));
        r4 = __fadd_rn(r4, __fmul_rn(a[i + 4], a[i + 4]));
        r5 = __fadd_rn(r5, __fmul_rn(a[i + 5], a[i + 5]));
        r6 = __fadd_rn(r6, __fmul_rn(a[i + 6], a[i + 6]));
        r7 = __fadd_rn(r7, __fmul_rn(a[i + 7], a[i + 7]));
    }
    float tA = __fadd_rn(__fadd_rn(r0, r1), __fadd_rn(r2, r3));
    float tB = __fadd_rn(__fadd_rn(r4, r5), __fadd_rn(r6, r7));
    return __fadd_rn(tA, tB);
}

// ---- codebook norms (numpy-exact) + fragment-ordered fp16 convert ----------
// cfrag[(s*64 + T)*64 + qd*16 + ln] = f16x8 of code (T*16+ln), dims s*32+qd*8..+7
__global__ void vq_prep(const float* __restrict__ cb, float* __restrict__ b2,
                        h8* __restrict__ cfrag) {
    int k = blockIdx.x * 256 + threadIdx.x;
    if (k >= K) return;
    const float* c = cb + (size_t)k * D;
    b2[k] = __fadd_rn(np_sq_block128(c), np_sq_block128(c + 128));
    int T = k >> 4, ln = k & 15;
    #pragma unroll
    for (int s = 0; s < 8; ++s)
        #pragma unroll
        for (int qd = 0; qd < 4; ++qd) {
            h8 f;
            #pragma unroll
            for (int j = 0; j < 8; ++j)
                f[j] = (_Float16)c[s * 32 + qd * 8 + j];
            cfrag[((size_t)(s * 64 + T)) * 64 + qd * 16 + ln] = f;
        }
}

// ---- fused MFMA distance GEMM + argmin + softmax stats + outputs -----------
// Block: 256 thr = 4 waves = 4 code-quarters; each wave: 32 rows x 256 codes.
// B staged per 32-dim K-step via global_load_lds (async DMA, zero VGPRs).
__global__ __launch_bounds__(256, 2)
void vq_mfma(const float* __restrict__ x, const float* __restrict__ cb,
             const h8* __restrict__ cfrag, const float* __restrict__ b2,
             float* __restrict__ avg_acc, float* __restrict__ scal,
             float* __restrict__ out)
{
    __shared__ __align__(16) h8 bbuf[4096];       // 64 KB B-stage, fragment order
    __shared__ float mred[4][32];
    __shared__ int   kred[4][32];
    __shared__ float sred[4][32];
    __shared__ float tred[4][32];
    __shared__ int   bkl[32];
    __shared__ int   candn[32];
    __shared__ int   candk[32][MAXCAND];
    __shared__ __align__(16) float xbuf[256];

    const int t   = threadIdx.x;
    const int w   = t >> 6;        // wave = code-quarter q (0..3)
    const int q   = w;
    const int l64 = t & 63;
    const int qd  = l64 >> 4;      // k-chunk (A/B) / row-subgroup (C)
    const int ln  = l64 & 15;      // m (A) / n (B) / col (C)
    const int r0  = blockIdx.x * 32;

    if (t < 32) candn[t] = 0;

    v4f acc[2][16];                // [row-tile][code-tile]
    #pragma unroll
    for (int rt = 0; rt < 2; ++rt)
        #pragma unroll
        for (int tt = 0; tt < 16; ++tt) acc[rt][tt] = (v4f)0.f;

    const float* ab[2] = { x + (size_t)(r0 + ln) * D,
                           x + (size_t)(r0 + 16 + ln) * D };

    // A prefetch for step 0 (4 float4 = 16 VGPRs)
    float4 pa[4];
    #pragma unroll
    for (int rt = 0; rt < 2; ++rt) {
        pa[2 * rt]     = *(const float4*)(ab[rt] + qd * 8);
        pa[2 * rt + 1] = *(const float4*)(ab[rt] + qd * 8 + 4);
    }

    for (int s = 0; s < 8; ++s) {
        __syncthreads();                           // step s-1 readers done
        // ---- B stage: wave w DMAs its own 16 tiles (1 KB contiguous each) ----
        #pragma unroll
        for (int kk = 0; kk < 16; ++kk) {
            int T = w * 16 + kk;
            const h8* gsrc = cfrag + ((size_t)(s * 64 + T)) * 64 + l64;
            __builtin_amdgcn_global_load_lds(
                (gas_u32p)(const void*)gsrc,
                (las_u32p)(void*)(bbuf + T * 64 + l64),
                16, 0, 0);
        }
        __syncthreads();                           // vmcnt drained -> stage visible

        h8 af[2];
        #pragma unroll
        for (int rt = 0; rt < 2; ++rt) {
            float4 a0 = pa[2 * rt], a1 = pa[2 * rt + 1];
            af[rt][0] = (_Float16)a0.x; af[rt][1] = (_Float16)a0.y;
            af[rt][2] = (_Float16)a0.z; af[rt][3] = (_Float16)a0.w;
            af[rt][4] = (_Float16)a1.x; af[rt][5] = (_Float16)a1.y;
            af[rt][6] = (_Float16)a1.z; af[rt][7] = (_Float16)a1.w;
        }
        if (s < 7) {                               // A prefetch for s+1
            #pragma unroll
            for (int rt = 0; rt < 2; ++rt) {
                pa[2 * rt]     = *(const float4*)(ab[rt] + (s + 1) * 32 + qd * 8);
                pa[2 * rt + 1] = *(const float4*)(ab[rt] + (s + 1) * 32 + qd * 8 + 4);
            }
        }
        #pragma unroll
        for (int tt = 0; tt < 16; ++tt) {
            h8 bf = bbuf[(16 * q + tt) * 64 + l64];
            acc[0][tt] = __builtin_amdgcn_mfma_f32_16x16x32_f16(af[0], bf, acc[0][tt], 0, 0, 0);
            acc[1][tt] = __builtin_amdgcn_mfma_f32_16x16x32_f16(af[1], bf, acc[1][tt], 0, 0, 0);
        }
    }

    // ---- z = 200*dot - 100*||c||^2 ----
    float b2c[16];
    #pragma unroll
    for (int tt = 0; tt < 16; ++tt) b2c[tt] = b2[256 * q + 16 * tt + ln];
    #pragma unroll
    for (int rt = 0; rt < 2; ++rt)
        #pragma unroll
        for (int tt = 0; tt < 16; ++tt)
            #pragma unroll
            for (int r = 0; r < 4; ++r)
                acc[rt][tt][r] = 200.f * acc[rt][tt][r] - 100.f * b2c[tt];

    // ---- per-row local max over this wave's 16 cols ----
    float m[2][4]; int bk[2][4];
    #pragma unroll
    for (int rt = 0; rt < 2; ++rt)
        #pragma unroll
        for (int r = 0; r < 4; ++r) { m[rt][r] = -INFINITY; bk[rt][r] = K; }
    #pragma unroll
    for (int tt = 0; tt < 16; ++tt)
        #pragma unroll
        for (int rt = 0; rt < 2; ++rt)
            #pragma unroll
            for (int r = 0; r < 4; ++r) {
                float z = acc[rt][tt][r];
                int code = 256 * q + 16 * tt + ln;
                if (z > m[rt][r]) { m[rt][r] = z; bk[rt][r] = code; }
            }
    #pragma unroll
    for (int off = 1; off < 16; off <<= 1)
        #pragma unroll
        for (int rt = 0; rt < 2; ++rt)
            #pragma unroll
            for (int r = 0; r < 4; ++r) {
                float om = __shfl_xor(m[rt][r], off);
                int   ok = __shfl_xor(bk[rt][r], off);
                if (om > m[rt][r] || (om == m[rt][r] && ok < bk[rt][r])) {
                    m[rt][r] = om; bk[rt][r] = ok;
                }
            }
    if (ln == 0)
        #pragma unroll
        for (int rt = 0; rt < 2; ++rt)
            #pragma unroll
            for (int r = 0; r < 4; ++r) {
                int rl = 16 * rt + 4 * qd + r;
                mred[q][rl] = m[rt][r]; kred[q][rl] = bk[rt][r];
            }
    __syncthreads();

    // ---- combine quarters (codes ascend with quarter -> '>' keeps low idx) --
    float mf[2][4]; int kf[2][4];
    #pragma unroll
    for (int rt = 0; rt < 2; ++rt)
        #pragma unroll
        for (int r = 0; r < 4; ++r) {
            int rl = 16 * rt + 4 * qd + r;
            mf[rt][r] = mred[0][rl]; kf[rt][r] = kred[0][rl];
            #pragma unroll
            for (int qq = 1; qq < 4; ++qq) {
                float mm = mred[qq][rl];
                if (mm > mf[rt][r]) { mf[rt][r] = mm; kf[rt][r] = kred[qq][rl]; }
            }
        }

    // ---- S,T with global max; candidate append; stash e-values ----
    float S[2][4] = {{0,0,0,0},{0,0,0,0}}, T[2][4] = {{0,0,0,0},{0,0,0,0}};
    #pragma unroll
    for (int tt = 0; tt < 16; ++tt)
        #pragma unroll
        for (int rt = 0; rt < 2; ++rt)
            #pragma unroll
            for (int r = 0; r < 4; ++r) {
                float z  = acc[rt][tt][r];
                float zz = z - mf[rt][r];
                float e  = __expf(zz);
                if (z > mf[rt][r] - MARGIN) {
                    int rl = 16 * rt + 4 * qd + r;
                    int slot = atomicAdd(&candn[rl], 1);
                    if (slot < MAXCAND) candk[rl][slot] = 256 * q + 16 * tt + ln;
                }
                S[rt][r] += e; T[rt][r] += zz * e;
                acc[rt][tt][r] = e;
            }
    #pragma unroll
    for (int off = 1; off < 16; off <<= 1)
        #pragma unroll
        for (int rt = 0; rt < 2; ++rt)
            #pragma unroll
            for (int r = 0; r < 4; ++r) {
                S[rt][r] += __shfl_xor(S[rt][r], off);
                T[rt][r] += __shfl_xor(T[rt][r], off);
            }
    if (ln == 0)
        #pragma unroll
        for (int rt = 0; rt < 2; ++rt)
            #pragma unroll
            for (int r = 0; r < 4; ++r) {
                int rl = 16 * rt + 4 * qd + r;
                sred[q][rl] = S[rt][r]; tred[q][rl] = T[rt][r];
            }
    __syncthreads();

    float iS[2][4];
    float hsum = 0.f;
    #pragma unroll
    for (int rt = 0; rt < 2; ++rt)
        #pragma unroll
        for (int r = 0; r < 4; ++r) {
            int rl = 16 * rt + 4 * qd + r;
            float Sf = sred[0][rl] + sred[1][rl] + sred[2][rl] + sred[3][rl];
            float Tf = tred[0][rl] + tred[1][rl] + tred[2][rl] + tred[3][rl];
            iS[rt][r] = 1.f / Sf;
            if (q == 0 && ln == 0) {
                bkl[rl] = kf[rt][r];
                hsum += Tf * iS[rt][r] - __logf(Sf);
            }
        }
    if (q == 0 && ln == 0) atomicAdd(&scal[1], hsum);

    // ---- sparse avg_probs emission ----
    #pragma unroll
    for (int tt = 0; tt < 16; ++tt)
        #pragma unroll
        for (int rt = 0; rt < 2; ++rt)
            #pragma unroll
            for (int r = 0; r < 4; ++r) {
                float p = acc[rt][tt][r] * iS[rt][r];
                if (p > 1e-12f)
                    atomicAdd(&avg_acc[256 * q + 16 * tt + ln], p);
            }
    __syncthreads();

    // ---- near-tie slow path (wave 0): numpy fp32-pipeline replica ----
    if (w == 0) {
        for (int row = 0; row < 32; ++row) {
            int tc = candn[row];
            if (tc < 2) continue;
            if (tc > MAXCAND) tc = MAXCAND;
            const float* xr = x + (size_t)(r0 + row) * D;
            *(float4*)&xbuf[l64 * 4] = *(const float4*)(xr + l64 * 4);
            float a2f = __fadd_rn(np_sq_block128(xbuf), np_sq_block128(xbuf + 128));
            float bestd = FLT_MAX; int bestk = K;
            for (int c = 0; c < tc; ++c) {
                int k = candk[row][c];
                double sdot = 0.0;
                #pragma unroll
                for (int dd = 0; dd < 4; ++dd)
                    sdot += (double)cb[(size_t)k * D + l64 * 4 + dd] *
                            (double)xbuf[l64 * 4 + dd];
                #pragma unroll
                for (int off = 32; off > 0; off >>= 1)
                    sdot += __shfl_xor(sdot, off);
                float abf = (float)sdot;
                float dnp = __fsub_rn(__fadd_rn(a2f, b2[k]), __fmul_rn(2.0f, abf));
                if (dnp < bestd || (dnp == bestd && k < bestk)) {
                    bestd = dnp; bestk = k;
                }
            }
            if (l64 == 0) bkl[row] = bestk;
        }
    }
    __syncthreads();

    // ---- outputs: wave w -> rows 8w..8w+7 ----
    float wmse = 0.f;
    #pragma unroll
    for (int rr = 0; rr < 8; ++rr) {
        int rl  = 8 * w + rr;
        int row = r0 + rl;
        int bk2 = bkl[rl];
        float4 xv = *(const float4*)(x  + (size_t)row * D + l64 * 4);
        float4 qv = *(const float4*)(cb + (size_t)bk2 * D + l64 * 4);
        float dx = qv.x - xv.x, dy = qv.y - xv.y, dz = qv.z - xv.z, dw = qv.w - xv.w;
        float4 st;
        st.x = xv.x + dx; st.y = xv.y + dy; st.z = xv.z + dz; st.w = xv.w + dw;
        *(float4*)(out + (size_t)row * D + l64 * 4) = st;
        if (l64 == 0) out[IDX_OFF + row] = (float)bk2;
        wmse += dx * dx + dy * dy + dz * dz + dw * dw;
    }
    #pragma unroll
    for (int off = 32; off > 0; off >>= 1)
        wmse += __shfl_xor(wmse, off);
    if (l64 == 0) atomicAdd(&scal[0], wmse);
}

// ---- finalize loss ----------------------------------------------------------
__global__ __launch_bounds__(1024)
void vq_fin(const float* __restrict__ avg_acc, const float* __restrict__ scal,
            float* __restrict__ out)
{
    __shared__ float sred[16];
    int t = threadIdx.x;
    float ap = avg_acc[t] * (1.f / 32768.f);
    float v = ap * logf(ap + 1e-5f);
    #pragma unroll
    for (int off = 32; off > 0; off >>= 1) v += __shfl_xor(v, off);
    if ((t & 63) == 0) sred[t >> 6] = v;
    __syncthreads();
    if (t == 0) {
        float s = 0.f;
        for (int w = 0; w < 16; ++w) s += sred[w];
        float avg_entropy = -s;
        float sampleH = -scal[1] * (1.f / 32768.f);
        float mse = scal[0] * (1.f / 8388608.f);
        float loss = 1.25f * mse + 0.1f * (sampleH - avg_entropy);
        out[LOSS_OFF] = loss;
    }
}

extern "C" void kernel_launch(void* const* d_in, const int* in_sizes, int n_in,
                              void* d_out, int out_size, void* d_ws, size_t ws_size,
                              hipStream_t stream)
{
    const float* x  = (const float*)d_in[0];
    const float* cb = (const float*)d_in[1];
    float* out = (float*)d_out;
    float* ws  = (float*)d_ws;
    float* b2      = ws;                                   // [1024]
    float* avg_acc = ws + K;                               // [1024]
    float* scal    = ws + 2 * K;                           // [2]
    h8*    cfrag   = (h8*)((char*)d_ws + 16384);           // [4096*64] frags (512 KB)

    hipMemsetAsync(d_ws, 0, (2 * K + 2) * sizeof(float), stream);
    vq_prep<<<K / 256, 256, 0, stream>>>(cb, b2, cfrag);
    vq_mfma<<<NROWS / 32, 256, 0, stream>>>(x, cb, cfrag, b2, avg_acc, scal, out);
    vq_fin<<<1, 1024, 0, stream>>>(avg_acc, scal, out);
}

// Round 7
// 205.412 us; speedup vs baseline: 1.8806x; 1.1321x over previous
//
#include <hip/hip_runtime.h>
#include <math.h>
#include <float.h>

#define D 256
#define K 1024
#define NROWS 32768
#define MARGIN 1.0f     // z-margin for np-replica near-tie refinement (fp16 fast-z)
#define MAXCAND 12

#define LOSS_OFF 8388608
#define IDX_OFF  8388609

typedef _Float16 h8 __attribute__((ext_vector_type(8)));
typedef float    v4f __attribute__((ext_vector_type(4)));
typedef const __attribute__((address_space(1))) unsigned int* gas_u32p;
typedef __attribute__((address_space(3))) unsigned int* las_u32p;

// ---- numpy pairwise sum replica for sum(a*a) over 128 contiguous floats ----
__device__ __forceinline__ float np_sq_block128(const float* a) {
    float r0 = __fmul_rn(a[0], a[0]);
    float r1 = __fmul_rn(a[1], a[1]);
    float r2 = __fmul_rn(a[2], a[2]);
    float r3 = __fmul_rn(a[3], a[3]);
    float r4 = __fmul_rn(a[4], a[4]);
    float r5 = __fmul_rn(a[5], a[5]);
    float r6 = __fmul_rn(a[6], a[6]);
    float r7 = __fmul_rn(a[7], a[7]);
    for (int i = 8; i < 128; i += 8) {
        r0 = __fadd_rn(r0, __fmul_rn(a[i + 0], a[i + 0]));
        r1 = __fadd_rn(r1, __fmul_rn(a[i + 1], a[i + 1]));
        r2 = __fadd_rn(r2, __fmul_rn(a[i + 2], a[i + 2]));
        r3 = __fadd_rn(r3, __fmul_rn(a[i + 3], a[i + 3]));
        r4 = __fadd_rn(r4, __fmul_rn(a[i + 4], a[i + 4]));
        r5 = __fadd_rn(r5, __fmul_rn(a[i + 5], a[i + 5]));
        r6 = __fadd_rn(r6, __fmul_rn(a[i + 6], a[i + 6]));
        r7 = __fadd_rn(r7, __fmul_rn(a[i + 7], a[i + 7]));
    }
    float tA = __fadd_rn(__fadd_rn(r0, r1), __fadd_rn(r2, r3));
    float tB = __fadd_rn(__fadd_rn(r4, r5), __fadd_rn(r6, r7));
    return __fadd_rn(tA, tB);
}

// ---- codebook squared norms (numpy pairwise replica), 16 blocks x 64 -------
__global__ void vq_b2w(const float* __restrict__ cb, float* __restrict__ b2) {
    int k = blockIdx.x * 64 + threadIdx.x;
    if (k >= K) return;
    const float* c = cb + (size_t)k * D;
    b2[k] = __fadd_rn(np_sq_block128(c), np_sq_block128(c + 128));
}

// ---- fragment-ordered fp16 convert: one h8 per thread, coalesced writes ----
// cfrag[(s*64 + T)*64 + qd*16 + ln] = f16x8 of code (T*16+ln), dims s*32+qd*8..+7
__global__ void vq_cvtw(const float* __restrict__ cb, h8* __restrict__ cfrag) {
    int tid = blockIdx.x * 256 + threadIdx.x;      // 0..32767
    int ln = tid & 15;
    int qd = (tid >> 4) & 3;
    int T  = (tid >> 6) & 63;
    int s  = tid >> 12;
    int k  = T * 16 + ln;
    const float* c = cb + (size_t)k * D + s * 32 + qd * 8;
    float4 v0 = *(const float4*)c;
    float4 v1 = *(const float4*)(c + 4);
    h8 f;
    f[0] = (_Float16)v0.x; f[1] = (_Float16)v0.y;
    f[2] = (_Float16)v0.z; f[3] = (_Float16)v0.w;
    f[4] = (_Float16)v1.x; f[5] = (_Float16)v1.y;
    f[6] = (_Float16)v1.z; f[7] = (_Float16)v1.w;
    cfrag[tid] = f;
}

// ---- fused MFMA distance GEMM + argmin + softmax stats + outputs -----------
// Block: 256 thr = 4 waves = 4 code-quarters; each wave: 32 rows x 256 codes.
// B staged per 32-dim K-step via global_load_lds (wave-uniform LDS base).
__global__ __launch_bounds__(256, 2)
void vq_mfma(const float* __restrict__ x, const float* __restrict__ cb,
             const h8* __restrict__ cfrag, const float* __restrict__ b2,
             float* __restrict__ avg_acc, float* __restrict__ scal,
             float* __restrict__ out)
{
    __shared__ __align__(16) h8 bbuf[4096];       // 64 KB B-stage, fragment order
    __shared__ float mred[4][32];
    __shared__ int   kred[4][32];
    __shared__ float sred[4][32];
    __shared__ float tred[4][32];
    __shared__ int   bkl[32];
    __shared__ int   candn[32];
    __shared__ int   candk[32][MAXCAND];
    __shared__ __align__(16) float xbuf[256];

    const int t   = threadIdx.x;
    const int w   = t >> 6;        // wave = code-quarter q (0..3)
    const int q   = w;
    const int l64 = t & 63;
    const int qd  = l64 >> 4;      // k-chunk (A/B) / row-subgroup (C)
    const int ln  = l64 & 15;      // m (A) / n (B) / col (C)
    const int r0  = blockIdx.x * 32;

    if (t < 32) candn[t] = 0;

    v4f acc[2][16];                // [row-tile][code-tile]
    #pragma unroll
    for (int rt = 0; rt < 2; ++rt)
        #pragma unroll
        for (int tt = 0; tt < 16; ++tt) acc[rt][tt] = (v4f)0.f;

    const float* ab[2] = { x + (size_t)(r0 + ln) * D,
                           x + (size_t)(r0 + 16 + ln) * D };

    // A prefetch for step 0 (4 float4 = 16 VGPRs)
    float4 pa[4];
    #pragma unroll
    for (int rt = 0; rt < 2; ++rt) {
        pa[2 * rt]     = *(const float4*)(ab[rt] + qd * 8);
        pa[2 * rt + 1] = *(const float4*)(ab[rt] + qd * 8 + 4);
    }

    for (int s = 0; s < 8; ++s) {
        __syncthreads();                           // step s-1 readers done
        // ---- B stage: wave w DMAs its 16 tiles; LDS base is WAVE-UNIFORM ----
        #pragma unroll
        for (int kk = 0; kk < 16; ++kk) {
            int T = w * 16 + kk;
            const h8* gsrc = cfrag + ((size_t)(s * 64 + T)) * 64 + l64;  // per-lane
            __builtin_amdgcn_global_load_lds(
                (gas_u32p)(const void*)gsrc,
                (las_u32p)(void*)(bbuf + T * 64),   // uniform; HW adds lane*16
                16, 0, 0);
        }
        __syncthreads();                           // vmcnt drained -> stage visible

        h8 af[2];
        #pragma unroll
        for (int rt = 0; rt < 2; ++rt) {
            float4 a0 = pa[2 * rt], a1 = pa[2 * rt + 1];
            af[rt][0] = (_Float16)a0.x; af[rt][1] = (_Float16)a0.y;
            af[rt][2] = (_Float16)a0.z; af[rt][3] = (_Float16)a0.w;
            af[rt][4] = (_Float16)a1.x; af[rt][5] = (_Float16)a1.y;
            af[rt][6] = (_Float16)a1.z; af[rt][7] = (_Float16)a1.w;
        }
        if (s < 7) {                               // A prefetch for s+1
            #pragma unroll
            for (int rt = 0; rt < 2; ++rt) {
                pa[2 * rt]     = *(const float4*)(ab[rt] + (s + 1) * 32 + qd * 8);
                pa[2 * rt + 1] = *(const float4*)(ab[rt] + (s + 1) * 32 + qd * 8 + 4);
            }
        }
        #pragma unroll
        for (int tt = 0; tt < 16; ++tt) {
            h8 bf = bbuf[(16 * q + tt) * 64 + l64];
            acc[0][tt] = __builtin_amdgcn_mfma_f32_16x16x32_f16(af[0], bf, acc[0][tt], 0, 0, 0);
            acc[1][tt] = __builtin_amdgcn_mfma_f32_16x16x32_f16(af[1], bf, acc[1][tt], 0, 0, 0);
        }
    }

    // ---- z = 200*dot - 100*||c||^2 ----
    float b2c[16];
    #pragma unroll
    for (int tt = 0; tt < 16; ++tt) b2c[tt] = b2[256 * q + 16 * tt + ln];
    #pragma unroll
    for (int rt = 0; rt < 2; ++rt)
        #pragma unroll
        for (int tt = 0; tt < 16; ++tt)
            #pragma unroll
            for (int r = 0; r < 4; ++r)
                acc[rt][tt][r] = 200.f * acc[rt][tt][r] - 100.f * b2c[tt];

    // ---- per-row local max over this wave's 16 cols ----
    float m[2][4]; int bk[2][4];
    #pragma unroll
    for (int rt = 0; rt < 2; ++rt)
        #pragma unroll
        for (int r = 0; r < 4; ++r) { m[rt][r] = -INFINITY; bk[rt][r] = K; }
    #pragma unroll
    for (int tt = 0; tt < 16; ++tt)
        #pragma unroll
        for (int rt = 0; rt < 2; ++rt)
            #pragma unroll
            for (int r = 0; r < 4; ++r) {
                float z = acc[rt][tt][r];
                int code = 256 * q + 16 * tt + ln;
                if (z > m[rt][r]) { m[rt][r] = z; bk[rt][r] = code; }
            }
    #pragma unroll
    for (int off = 1; off < 16; off <<= 1)
        #pragma unroll
        for (int rt = 0; rt < 2; ++rt)
            #pragma unroll
            for (int r = 0; r < 4; ++r) {
                float om = __shfl_xor(m[rt][r], off);
                int   ok = __shfl_xor(bk[rt][r], off);
                if (om > m[rt][r] || (om == m[rt][r] && ok < bk[rt][r])) {
                    m[rt][r] = om; bk[rt][r] = ok;
                }
            }
    if (ln == 0)
        #pragma unroll
        for (int rt = 0; rt < 2; ++rt)
            #pragma unroll
            for (int r = 0; r < 4; ++r) {
                int rl = 16 * rt + 4 * qd + r;
                mred[q][rl] = m[rt][r]; kred[q][rl] = bk[rt][r];
            }
    __syncthreads();

    // ---- combine quarters (codes ascend with quarter -> '>' keeps low idx) --
    float mf[2][4]; int kf[2][4];
    #pragma unroll
    for (int rt = 0; rt < 2; ++rt)
        #pragma unroll
        for (int r = 0; r < 4; ++r) {
            int rl = 16 * rt + 4 * qd + r;
            mf[rt][r] = mred[0][rl]; kf[rt][r] = kred[0][rl];
            #pragma unroll
            for (int qq = 1; qq < 4; ++qq) {
                float mm = mred[qq][rl];
                if (mm > mf[rt][r]) { mf[rt][r] = mm; kf[rt][r] = kred[qq][rl]; }
            }
        }

    // ---- S,T with global max; candidate append; stash e-values ----
    float S[2][4] = {{0,0,0,0},{0,0,0,0}}, T[2][4] = {{0,0,0,0},{0,0,0,0}};
    #pragma unroll
    for (int tt = 0; tt < 16; ++tt)
        #pragma unroll
        for (int rt = 0; rt < 2; ++rt)
            #pragma unroll
            for (int r = 0; r < 4; ++r) {
                float z  = acc[rt][tt][r];
                float zz = z - mf[rt][r];
                float e  = __expf(zz);
                if (z > mf[rt][r] - MARGIN) {
                    int rl = 16 * rt + 4 * qd + r;
                    int slot = atomicAdd(&candn[rl], 1);
                    if (slot < MAXCAND) candk[rl][slot] = 256 * q + 16 * tt + ln;
                }
                S[rt][r] += e; T[rt][r] += zz * e;
                acc[rt][tt][r] = e;
            }
    #pragma unroll
    for (int off = 1; off < 16; off <<= 1)
        #pragma unroll
        for (int rt = 0; rt < 2; ++rt)
            #pragma unroll
            for (int r = 0; r < 4; ++r) {
                S[rt][r] += __shfl_xor(S[rt][r], off);
                T[rt][r] += __shfl_xor(T[rt][r], off);
            }
    if (ln == 0)
        #pragma unroll
        for (int rt = 0; rt < 2; ++rt)
            #pragma unroll
            for (int r = 0; r < 4; ++r) {
                int rl = 16 * rt + 4 * qd + r;
                sred[q][rl] = S[rt][r]; tred[q][rl] = T[rt][r];
            }
    __syncthreads();

    float iS[2][4];
    float hsum = 0.f;
    #pragma unroll
    for (int rt = 0; rt < 2; ++rt)
        #pragma unroll
        for (int r = 0; r < 4; ++r) {
            int rl = 16 * rt + 4 * qd + r;
            float Sf = sred[0][rl] + sred[1][rl] + sred[2][rl] + sred[3][rl];
            float Tf = tred[0][rl] + tred[1][rl] + tred[2][rl] + tred[3][rl];
            iS[rt][r] = 1.f / Sf;
            if (q == 0 && ln == 0) {
                bkl[rl] = kf[rt][r];
                hsum += Tf * iS[rt][r] - __logf(Sf);
            }
        }
    if (q == 0 && ln == 0) atomicAdd(&scal[1], hsum);

    // ---- sparse avg_probs emission ----
    #pragma unroll
    for (int tt = 0; tt < 16; ++tt)
        #pragma unroll
        for (int rt = 0; rt < 2; ++rt)
            #pragma unroll
            for (int r = 0; r < 4; ++r) {
                float p = acc[rt][tt][r] * iS[rt][r];
                if (p > 1e-12f)
                    atomicAdd(&avg_acc[256 * q + 16 * tt + ln], p);
            }
    __syncthreads();

    // ---- near-tie slow path (wave 0): numpy fp32-pipeline replica ----
    if (w == 0) {
        for (int row = 0; row < 32; ++row) {
            int tc = candn[row];
            if (tc < 2) continue;
            if (tc > MAXCAND) tc = MAXCAND;
            const float* xr = x + (size_t)(r0 + row) * D;
            *(float4*)&xbuf[l64 * 4] = *(const float4*)(xr + l64 * 4);
            float a2f = __fadd_rn(np_sq_block128(xbuf), np_sq_block128(xbuf + 128));
            float bestd = FLT_MAX; int bestk = K;
            for (int c = 0; c < tc; ++c) {
                int k = candk[row][c];
                double sdot = 0.0;
                #pragma unroll
                for (int dd = 0; dd < 4; ++dd)
                    sdot += (double)cb[(size_t)k * D + l64 * 4 + dd] *
                            (double)xbuf[l64 * 4 + dd];
                #pragma unroll
                for (int off = 32; off > 0; off >>= 1)
                    sdot += __shfl_xor(sdot, off);
                float abf = (float)sdot;
                float dnp = __fsub_rn(__fadd_rn(a2f, b2[k]), __fmul_rn(2.0f, abf));
                if (dnp < bestd || (dnp == bestd && k < bestk)) {
                    bestd = dnp; bestk = k;
                }
            }
            if (l64 == 0) bkl[row] = bestk;
        }
    }
    __syncthreads();

    // ---- outputs: wave w -> rows 8w..8w+7 ----
    float wmse = 0.f;
    #pragma unroll
    for (int rr = 0; rr < 8; ++rr) {
        int rl  = 8 * w + rr;
        int row = r0 + rl;
        int bk2 = bkl[rl];
        float4 xv = *(const float4*)(x  + (size_t)row * D + l64 * 4);
        float4 qv = *(const float4*)(cb + (size_t)bk2 * D + l64 * 4);
        float dx = qv.x - xv.x, dy = qv.y - xv.y, dz = qv.z - xv.z, dw = qv.w - xv.w;
        float4 st;
        st.x = xv.x + dx; st.y = xv.y + dy; st.z = xv.z + dz; st.w = xv.w + dw;
        *(float4*)(out + (size_t)row * D + l64 * 4) = st;
        if (l64 == 0) out[IDX_OFF + row] = (float)bk2;
        wmse += dx * dx + dy * dy + dz * dz + dw * dw;
    }
    #pragma unroll
    for (int off = 32; off > 0; off >>= 1)
        wmse += __shfl_xor(wmse, off);
    if (l64 == 0) atomicAdd(&scal[0], wmse);
}

// ---- finalize loss ----------------------------------------------------------
__global__ __launch_bounds__(1024)
void vq_fin(const float* __restrict__ avg_acc, const float* __restrict__ scal,
            float* __restrict__ out)
{
    __shared__ float sred[16];
    int t = threadIdx.x;
    float ap = avg_acc[t] * (1.f / 32768.f);
    float v = ap * logf(ap + 1e-5f);
    #pragma unroll
    for (int off = 32; off > 0; off >>= 1) v += __shfl_xor(v, off);
    if ((t & 63) == 0) sred[t >> 6] = v;
    __syncthreads();
    if (t == 0) {
        float s = 0.f;
        for (int w = 0; w < 16; ++w) s += sred[w];
        float avg_entropy = -s;
        float sampleH = -scal[1] * (1.f / 32768.f);
        float mse = scal[0] * (1.f / 8388608.f);
        float loss = 1.25f * mse + 0.1f * (sampleH - avg_entropy);
        out[LOSS_OFF] = loss;
    }
}

extern "C" void kernel_launch(void* const* d_in, const int* in_sizes, int n_in,
                              void* d_out, int out_size, void* d_ws, size_t ws_size,
                              hipStream_t stream)
{
    const float* x  = (const float*)d_in[0];
    const float* cb = (const float*)d_in[1];
    float* out = (float*)d_out;
    float* ws  = (float*)d_ws;
    float* b2      = ws;                                   // [1024]
    float* avg_acc = ws + K;                               // [1024]
    float* scal    = ws + 2 * K;                           // [2]
    h8*    cfrag   = (h8*)((char*)d_ws + 16384);           // [4096*64] frags (512 KB)

    hipMemsetAsync(d_ws, 0, (2 * K + 2) * sizeof(float), stream);
    vq_b2w <<<16, 64, 0, stream>>>(cb, b2);
    vq_cvtw<<<128, 256, 0, stream>>>(cb, cfrag);
    vq_mfma<<<NROWS / 32, 256, 0, stream>>>(x, cb, cfrag, b2, avg_acc, scal, out);
    vq_fin<<<1, 1024, 0, stream>>>(avg_acc, scal, out);
}

// Round 8
// 200.458 us; speedup vs baseline: 1.9271x; 1.0247x over previous
//
#include <hip/hip_runtime.h>
#include <math.h>
#include <float.h>

#define D 256
#define K 1024
#define NROWS 32768
#define MARGIN 1.0f     // z-margin for np-replica near-tie refinement (fp16 fast-z)
#define MAXCAND 12

#define LOSS_OFF 8388608
#define IDX_OFF  8388609

typedef _Float16 h8 __attribute__((ext_vector_type(8)));
typedef float    v4f __attribute__((ext_vector_type(4)));
typedef const __attribute__((address_space(1))) unsigned int* gas_u32p;
typedef __attribute__((address_space(3))) unsigned int* las_u32p;

// ---- numpy pairwise sum replica for sum(a*a) over 128 contiguous floats ----
__device__ __forceinline__ float np_sq_block128(const float* a) {
    float r0 = __fmul_rn(a[0], a[0]);
    float r1 = __fmul_rn(a[1], a[1]);
    float r2 = __fmul_rn(a[2], a[2]);
    float r3 = __fmul_rn(a[3], a[3]);
    float r4 = __fmul_rn(a[4], a[4]);
    float r5 = __fmul_rn(a[5], a[5]);
    float r6 = __fmul_rn(a[6], a[6]);
    float r7 = __fmul_rn(a[7], a[7]);
    for (int i = 8; i < 128; i += 8) {
        r0 = __fadd_rn(r0, __fmul_rn(a[i + 0], a[i + 0]));
        r1 = __fadd_rn(r1, __fmul_rn(a[i + 1], a[i + 1]));
        r2 = __fadd_rn(r2, __fmul_rn(a[i + 2], a[i + 2]));
        r3 = __fadd_rn(r3, __fmul_rn(a[i + 3], a[i + 3]));
        r4 = __fadd_rn(r4, __fmul_rn(a[i + 4], a[i + 4]));
        r5 = __fadd_rn(r5, __fmul_rn(a[i + 5], a[i + 5]));
        r6 = __fadd_rn(r6, __fmul_rn(a[i + 6], a[i + 6]));
        r7 = __fadd_rn(r7, __fmul_rn(a[i + 7], a[i + 7]));
    }
    float tA = __fadd_rn(__fadd_rn(r0, r1), __fadd_rn(r2, r3));
    float tB = __fadd_rn(__fadd_rn(r4, r5), __fadd_rn(r6, r7));
    return __fadd_rn(tA, tB);
}

// ---- fused prep: fragment convert + b2 (numpy-exact) + ws zeroing ----------
// cfrag[(s*64 + T)*64 + qd*16 + ln] = f16x8 of code (T*16+ln), dims s*32+qd*8..+7
__global__ void vq_prep(const float* __restrict__ cb, float* __restrict__ b2,
                        h8* __restrict__ cfrag, float* __restrict__ avg_acc,
                        float* __restrict__ scal) {
    int tid = blockIdx.x * 256 + threadIdx.x;      // 0..32767
    // fragment-ordered fp16 convert (coalesced 16B writes)
    {
        int ln = tid & 15;
        int qd = (tid >> 4) & 3;
        int T  = (tid >> 6) & 63;
        int s  = tid >> 12;
        int k  = T * 16 + ln;
        const float* c = cb + (size_t)k * D + s * 32 + qd * 8;
        float4 v0 = *(const float4*)c;
        float4 v1 = *(const float4*)(c + 4);
        h8 f;
        f[0] = (_Float16)v0.x; f[1] = (_Float16)v0.y;
        f[2] = (_Float16)v0.z; f[3] = (_Float16)v0.w;
        f[4] = (_Float16)v1.x; f[5] = (_Float16)v1.y;
        f[6] = (_Float16)v1.z; f[7] = (_Float16)v1.w;
        cfrag[tid] = f;
    }
    // numpy-exact codebook norms
    if (tid < K) {
        const float* c = cb + (size_t)tid * D;
        b2[tid] = __fadd_rn(np_sq_block128(c), np_sq_block128(c + 128));
    }
    // zero the accumulators (kernel-order guarantees visibility before vq_mfma)
    if (tid >= 1024 && tid < 2048) avg_acc[tid - 1024] = 0.f;
    if (tid >= 2048 && tid < 2050) scal[tid - 2048] = 0.f;
}

// ---- fused MFMA distance GEMM + argmin + softmax stats + outputs -----------
// Block: 256 thr = 4 waves = 4 code-quarters; each wave: 32 rows x 256 codes.
// bbuf is WAVE-PRIVATE (wave w writes and reads only T in [16w,16w+16)) ->
// no __syncthreads in the K-loop; per-wave s_waitcnt vmcnt(0) instead.
__global__ __launch_bounds__(256, 2)
void vq_mfma(const float* __restrict__ x, const float* __restrict__ cb,
             const h8* __restrict__ cfrag, const float* __restrict__ b2,
             float* __restrict__ avg_acc, float* __restrict__ scal,
             float* __restrict__ out)
{
    __shared__ __align__(16) h8 bbuf[4096];       // 64 KB B-stage, fragment order
    __shared__ float mred[4][32];
    __shared__ int   kred[4][32];
    __shared__ float sred[4][32];
    __shared__ float tred[4][32];
    __shared__ int   bkl[32];
    __shared__ int   candn[32];
    __shared__ int   candk[32][MAXCAND];
    __shared__ __align__(16) float xbuf[256];

    const int t   = threadIdx.x;
    const int w   = t >> 6;        // wave = code-quarter q (0..3)
    const int q   = w;
    const int l64 = t & 63;
    const int qd  = l64 >> 4;      // k-chunk (A/B) / row-subgroup (C)
    const int ln  = l64 & 15;      // m (A) / n (B) / col (C)
    const int r0  = blockIdx.x * 32;

    if (t < 32) candn[t] = 0;

    v4f acc[2][16];                // [row-tile][code-tile]
    #pragma unroll
    for (int rt = 0; rt < 2; ++rt)
        #pragma unroll
        for (int tt = 0; tt < 16; ++tt) acc[rt][tt] = (v4f)0.f;

    const float* ab[2] = { x + (size_t)(r0 + ln) * D,
                           x + (size_t)(r0 + 16 + ln) * D };

    // A prefetch for step 0 (4 float4 = 16 VGPRs)
    float4 pa[4];
    #pragma unroll
    for (int rt = 0; rt < 2; ++rt) {
        pa[2 * rt]     = *(const float4*)(ab[rt] + qd * 8);
        pa[2 * rt + 1] = *(const float4*)(ab[rt] + qd * 8 + 4);
    }

    for (int s = 0; s < 8; ++s) {
        // ---- B stage: wave w DMAs its own 16 tiles (wave-private region) ----
        #pragma unroll
        for (int kk = 0; kk < 16; ++kk) {
            int T = w * 16 + kk;
            const h8* gsrc = cfrag + ((size_t)(s * 64 + T)) * 64 + l64;
            __builtin_amdgcn_global_load_lds(
                (gas_u32p)(const void*)gsrc,
                (las_u32p)(void*)(bbuf + T * 64),   // uniform base; HW adds lane*16
                16, 0, 0);
        }
        // per-wave drain: B-DMAs (and last step's A-prefetch) complete
        asm volatile("s_waitcnt vmcnt(0)" ::: "memory");

        h8 af[2];
        #pragma unroll
        for (int rt = 0; rt < 2; ++rt) {
            float4 a0 = pa[2 * rt], a1 = pa[2 * rt + 1];
            af[rt][0] = (_Float16)a0.x; af[rt][1] = (_Float16)a0.y;
            af[rt][2] = (_Float16)a0.z; af[rt][3] = (_Float16)a0.w;
            af[rt][4] = (_Float16)a1.x; af[rt][5] = (_Float16)a1.y;
            af[rt][6] = (_Float16)a1.z; af[rt][7] = (_Float16)a1.w;
        }
        if (s < 7) {                               // A prefetch for s+1
            #pragma unroll
            for (int rt = 0; rt < 2; ++rt) {
                pa[2 * rt]     = *(const float4*)(ab[rt] + (s + 1) * 32 + qd * 8);
                pa[2 * rt + 1] = *(const float4*)(ab[rt] + (s + 1) * 32 + qd * 8 + 4);
            }
        }
        #pragma unroll
        for (int tt = 0; tt < 16; ++tt) {
            h8 bf = bbuf[(16 * q + tt) * 64 + l64];
            acc[0][tt] = __builtin_amdgcn_mfma_f32_16x16x32_f16(af[0], bf, acc[0][tt], 0, 0, 0);
            acc[1][tt] = __builtin_amdgcn_mfma_f32_16x16x32_f16(af[1], bf, acc[1][tt], 0, 0, 0);
        }
    }

    // ---- z = 200*dot - 100*||c||^2 ----
    float b2c[16];
    #pragma unroll
    for (int tt = 0; tt < 16; ++tt) b2c[tt] = b2[256 * q + 16 * tt + ln];
    #pragma unroll
    for (int rt = 0; rt < 2; ++rt)
        #pragma unroll
        for (int tt = 0; tt < 16; ++tt)
            #pragma unroll
            for (int r = 0; r < 4; ++r)
                acc[rt][tt][r] = 200.f * acc[rt][tt][r] - 100.f * b2c[tt];

    // ---- per-row local max over this wave's 16 cols ----
    float m[2][4]; int bk[2][4];
    #pragma unroll
    for (int rt = 0; rt < 2; ++rt)
        #pragma unroll
        for (int r = 0; r < 4; ++r) { m[rt][r] = -INFINITY; bk[rt][r] = K; }
    #pragma unroll
    for (int tt = 0; tt < 16; ++tt)
        #pragma unroll
        for (int rt = 0; rt < 2; ++rt)
            #pragma unroll
            for (int r = 0; r < 4; ++r) {
                float z = acc[rt][tt][r];
                int code = 256 * q + 16 * tt + ln;
                if (z > m[rt][r]) { m[rt][r] = z; bk[rt][r] = code; }
            }
    #pragma unroll
    for (int off = 1; off < 16; off <<= 1)
        #pragma unroll
        for (int rt = 0; rt < 2; ++rt)
            #pragma unroll
            for (int r = 0; r < 4; ++r) {
                float om = __shfl_xor(m[rt][r], off);
                int   ok = __shfl_xor(bk[rt][r], off);
                if (om > m[rt][r] || (om == m[rt][r] && ok < bk[rt][r])) {
                    m[rt][r] = om; bk[rt][r] = ok;
                }
            }
    if (ln == 0)
        #pragma unroll
        for (int rt = 0; rt < 2; ++rt)
            #pragma unroll
            for (int r = 0; r < 4; ++r) {
                int rl = 16 * rt + 4 * qd + r;
                mred[q][rl] = m[rt][r]; kred[q][rl] = bk[rt][r];
            }
    __syncthreads();

    // ---- combine quarters (codes ascend with quarter -> '>' keeps low idx) --
    float mf[2][4]; int kf[2][4];
    #pragma unroll
    for (int rt = 0; rt < 2; ++rt)
        #pragma unroll
        for (int r = 0; r < 4; ++r) {
            int rl = 16 * rt + 4 * qd + r;
            mf[rt][r] = mred[0][rl]; kf[rt][r] = kred[0][rl];
            #pragma unroll
            for (int qq = 1; qq < 4; ++qq) {
                float mm = mred[qq][rl];
                if (mm > mf[rt][r]) { mf[rt][r] = mm; kf[rt][r] = kred[qq][rl]; }
            }
        }

    // ---- S,T with global max; candidate append; stash e-values ----
    float S[2][4] = {{0,0,0,0},{0,0,0,0}}, T[2][4] = {{0,0,0,0},{0,0,0,0}};
    #pragma unroll
    for (int tt = 0; tt < 16; ++tt)
        #pragma unroll
        for (int rt = 0; rt < 2; ++rt)
            #pragma unroll
            for (int r = 0; r < 4; ++r) {
                float z  = acc[rt][tt][r];
                float zz = z - mf[rt][r];
                float e  = __expf(zz);
                if (z > mf[rt][r] - MARGIN) {
                    int rl = 16 * rt + 4 * qd + r;
                    int slot = atomicAdd(&candn[rl], 1);
                    if (slot < MAXCAND) candk[rl][slot] = 256 * q + 16 * tt + ln;
                }
                S[rt][r] += e; T[rt][r] += zz * e;
                acc[rt][tt][r] = e;
            }
    #pragma unroll
    for (int off = 1; off < 16; off <<= 1)
        #pragma unroll
        for (int rt = 0; rt < 2; ++rt)
            #pragma unroll
            for (int r = 0; r < 4; ++r) {
                S[rt][r] += __shfl_xor(S[rt][r], off);
                T[rt][r] += __shfl_xor(T[rt][r], off);
            }
    if (ln == 0)
        #pragma unroll
        for (int rt = 0; rt < 2; ++rt)
            #pragma unroll
            for (int r = 0; r < 4; ++r) {
                int rl = 16 * rt + 4 * qd + r;
                sred[q][rl] = S[rt][r]; tred[q][rl] = T[rt][r];
            }
    __syncthreads();

    float iS[2][4];
    float hsum = 0.f;
    #pragma unroll
    for (int rt = 0; rt < 2; ++rt)
        #pragma unroll
        for (int r = 0; r < 4; ++r) {
            int rl = 16 * rt + 4 * qd + r;
            float Sf = sred[0][rl] + sred[1][rl] + sred[2][rl] + sred[3][rl];
            float Tf = tred[0][rl] + tred[1][rl] + tred[2][rl] + tred[3][rl];
            iS[rt][r] = 1.f / Sf;
            if (q == 0 && ln == 0) {
                bkl[rl] = kf[rt][r];
                hsum += Tf * iS[rt][r] - __logf(Sf);
            }
        }
    if (q == 0 && ln == 0) atomicAdd(&scal[1], hsum);

    // ---- sparse avg_probs emission ----
    #pragma unroll
    for (int tt = 0; tt < 16; ++tt)
        #pragma unroll
        for (int rt = 0; rt < 2; ++rt)
            #pragma unroll
            for (int r = 0; r < 4; ++r) {
                float p = acc[rt][tt][r] * iS[rt][r];
                if (p > 1e-12f)
                    atomicAdd(&avg_acc[256 * q + 16 * tt + ln], p);
            }
    __syncthreads();

    // ---- near-tie slow path (wave 0): numpy fp32-pipeline replica ----
    if (w == 0) {
        for (int row = 0; row < 32; ++row) {
            int tc = candn[row];
            if (tc < 2) continue;
            if (tc > MAXCAND) tc = MAXCAND;
            const float* xr = x + (size_t)(r0 + row) * D;
            *(float4*)&xbuf[l64 * 4] = *(const float4*)(xr + l64 * 4);
            float a2f = __fadd_rn(np_sq_block128(xbuf), np_sq_block128(xbuf + 128));
            float bestd = FLT_MAX; int bestk = K;
            for (int c = 0; c < tc; ++c) {
                int k = candk[row][c];
                double sdot = 0.0;
                #pragma unroll
                for (int dd = 0; dd < 4; ++dd)
                    sdot += (double)cb[(size_t)k * D + l64 * 4 + dd] *
                            (double)xbuf[l64 * 4 + dd];
                #pragma unroll
                for (int off = 32; off > 0; off >>= 1)
                    sdot += __shfl_xor(sdot, off);
                float abf = (float)sdot;
                float dnp = __fsub_rn(__fadd_rn(a2f, b2[k]), __fmul_rn(2.0f, abf));
                if (dnp < bestd || (dnp == bestd && k < bestk)) {
                    bestd = dnp; bestk = k;
                }
            }
            if (l64 == 0) bkl[row] = bestk;
        }
    }
    __syncthreads();

    // ---- outputs: wave w -> rows 8w..8w+7 ----
    float wmse = 0.f;
    #pragma unroll
    for (int rr = 0; rr < 8; ++rr) {
        int rl  = 8 * w + rr;
        int row = r0 + rl;
        int bk2 = bkl[rl];
        float4 xv = *(const float4*)(x  + (size_t)row * D + l64 * 4);
        float4 qv = *(const float4*)(cb + (size_t)bk2 * D + l64 * 4);
        float dx = qv.x - xv.x, dy = qv.y - xv.y, dz = qv.z - xv.z, dw = qv.w - xv.w;
        float4 st;
        st.x = xv.x + dx; st.y = xv.y + dy; st.z = xv.z + dz; st.w = xv.w + dw;
        *(float4*)(out + (size_t)row * D + l64 * 4) = st;
        if (l64 == 0) out[IDX_OFF + row] = (float)bk2;
        wmse += dx * dx + dy * dy + dz * dz + dw * dw;
    }
    #pragma unroll
    for (int off = 32; off > 0; off >>= 1)
        wmse += __shfl_xor(wmse, off);
    if (l64 == 0) atomicAdd(&scal[0], wmse);
}

// ---- finalize loss ----------------------------------------------------------
__global__ __launch_bounds__(1024)
void vq_fin(const float* __restrict__ avg_acc, const float* __restrict__ scal,
            float* __restrict__ out)
{
    __shared__ float sred[16];
    int t = threadIdx.x;
    float ap = avg_acc[t] * (1.f / 32768.f);
    float v = ap * logf(ap + 1e-5f);
    #pragma unroll
    for (int off = 32; off > 0; off >>= 1) v += __shfl_xor(v, off);
    if ((t & 63) == 0) sred[t >> 6] = v;
    __syncthreads();
    if (t == 0) {
        float s = 0.f;
        for (int w = 0; w < 16; ++w) s += sred[w];
        float avg_entropy = -s;
        float sampleH = -scal[1] * (1.f / 32768.f);
        float mse = scal[0] * (1.f / 8388608.f);
        float loss = 1.25f * mse + 0.1f * (sampleH - avg_entropy);
        out[LOSS_OFF] = loss;
    }
}

extern "C" void kernel_launch(void* const* d_in, const int* in_sizes, int n_in,
                              void* d_out, int out_size, void* d_ws, size_t ws_size,
                              hipStream_t stream)
{
    const float* x  = (const float*)d_in[0];
    const float* cb = (const float*)d_in[1];
    float* out = (float*)d_out;
    float* ws  = (float*)d_ws;
    float* b2      = ws;                                   // [1024]
    float* avg_acc = ws + K;                               // [1024]
    float* scal    = ws + 2 * K;                           // [2]
    h8*    cfrag   = (h8*)((char*)d_ws + 16384);           // [4096*64] frags (512 KB)

    vq_prep<<<128, 256, 0, stream>>>(cb, b2, cfrag, avg_acc, scal);
    vq_mfma<<<NROWS / 32, 256, 0, stream>>>(x, cb, cfrag, b2, avg_acc, scal, out);
    vq_fin<<<1, 1024, 0, stream>>>(avg_acc, scal, out);
}